// Round 15
// baseline (192.255 us; speedup 1.0000x reference)
//
#include <hip/hip_runtime.h>

// Self-attention: B=4, S=2048, E=1024, H=16, D=64, causal, scale=1/32, fp32 I/O.
// Pipeline: cvt->bf16 (1 launch), QKV GEMM (MFMA + global_load_lds),
// flash attention (32x32 swapped-operand, in-register softmax, KVBLK=256),
// out GEMM (global_load_lds) + bias.
// R15: complementary-qt pairing. CU c co-hosts blocks c and c+256; map
// qt = (g>>6)<4 ? 7-(g>>6) : (g>>6)-4 so the pair's qt sums to 7 -> every CU
// gets uniform ~264 wave-subtiles (was 360..160, 2.25x skew = the 88us wall).
// Pair shares bh -> short block's K/V reads are L2-hot. Body = R14 verbatim.

#define E_DIM 1024
#define S_LEN 2048
#define BATCH 4
#define NHEAD 16
#define HDIM  64

using short8 = __attribute__((ext_vector_type(8))) short;
using f32x4  = __attribute__((ext_vector_type(4))) float;
using f32x16 = __attribute__((ext_vector_type(16))) float;
using i32x4  = __attribute__((ext_vector_type(4))) int;

// async global->LDS, 16B per lane; lds dest = wave-uniform base + lane*16
#define GLD16(gp, lp) __builtin_amdgcn_global_load_lds( \
    (const __attribute__((address_space(1))) void*)(gp), \
    (__attribute__((address_space(3))) void*)(lp), 16, 0, 0)

__device__ inline unsigned short f2bf(float f) {
    unsigned int u = __builtin_bit_cast(unsigned int, f);
    u += 0x7FFFu + ((u >> 16) & 1u);   // round-to-nearest-even
    return (unsigned short)(u >> 16);
}

// packed f32 pair -> bf16x2 (lo16 = a, hi16 = b)
__device__ inline unsigned int cvt_pk_bf16(float a, float b) {
    unsigned int r;
    asm("v_cvt_pk_bf16_f32 %0, %1, %2" : "=v"(r) : "v"(a), "v"(b));
    return r;
}

// ---------------- fused fp32 -> bf16 convert (x + 4 weights, one launch) ----------------
__global__ __launch_bounds__(256) void cvt_all(
        const float* __restrict__ x,  const float* __restrict__ wq,
        const float* __restrict__ wk, const float* __restrict__ wv,
        const float* __restrict__ wo,
        unsigned short* __restrict__ xb, unsigned short* __restrict__ wb) {
    const int bid = blockIdx.x;
    const float* src;
    unsigned short* dst;
    int blk;
    if (bid < 8192) { src = x; dst = xb; blk = bid; }
    else {
        const int wsel = (bid - 8192) >> 10;          // 0..3
        blk = (bid - 8192) & 1023;
        src = (wsel == 0) ? wq : (wsel == 1) ? wk : (wsel == 2) ? wv : wo;
        dst = wb + (size_t)wsel * 1048576;
    }
    const int i = (blk * 256 + threadIdx.x) * 4;
    float4 v = *reinterpret_cast<const float4*>(src + i);
    ushort4 o;
    o.x = f2bf(v.x); o.y = f2bf(v.y); o.z = f2bf(v.z); o.w = f2bf(v.w);
    *reinterpret_cast<ushort4*>(dst + i) = o;
}

// ---------------- QKV projection GEMM (global_load_lds staging) ----------------
__global__ __launch_bounds__(256) void gemm_qkv(
        const unsigned short* __restrict__ xb,
        const unsigned short* __restrict__ wb,
        unsigned short* __restrict__ qkv) {
    const int z = blockIdx.z;
    const unsigned short* Bw = wb + (size_t)z * (E_DIM * E_DIM);
    unsigned short* Out = qkv + (size_t)z * ((size_t)BATCH * NHEAD * S_LEN * HDIM);
    const int m0 = blockIdx.x * 128, n0 = blockIdx.y * 128;
    const int tid = threadIdx.x;
    const int lane = tid & 63, w = tid >> 6;
    const int wm = w >> 1, wn = w & 1;
    const int col = lane & 15, hi = lane >> 4;

    __shared__ __align__(16) unsigned short Alds[128 * 32];
    __shared__ __align__(16) unsigned short Blds[128 * 32];

    const int srow = tid >> 2;               // 0..63
    const int sc8  = (tid & 3) * 8;          // k-chunk
    const int wofs = w * 512;                // wave-uniform LDS base (elements)

    f32x4 acc[4][4] = {};

    for (int kt = 0; kt < E_DIM / 32; ++kt) {
        const int k0 = kt * 32;
        GLD16(xb + (size_t)(m0 + srow) * E_DIM + k0 + sc8,       &Alds[wofs]);
        GLD16(xb + (size_t)(m0 + 64 + srow) * E_DIM + k0 + sc8,  &Alds[2048 + wofs]);
        GLD16(Bw + (size_t)(n0 + srow) * E_DIM + k0 + sc8,       &Blds[wofs]);
        GLD16(Bw + (size_t)(n0 + 64 + srow) * E_DIM + k0 + sc8,  &Blds[2048 + wofs]);
        __syncthreads();
        short8 af[4], bf[4];
#pragma unroll
        for (int mt = 0; mt < 4; ++mt)
            af[mt] = *reinterpret_cast<const short8*>(&Alds[(wm * 64 + mt * 16 + col) * 32 + hi * 8]);
#pragma unroll
        for (int nt = 0; nt < 4; ++nt)
            bf[nt] = *reinterpret_cast<const short8*>(&Blds[(wn * 64 + nt * 16 + col) * 32 + hi * 8]);
#pragma unroll
        for (int mt = 0; mt < 4; ++mt)
#pragma unroll
            for (int nt = 0; nt < 4; ++nt)
                acc[mt][nt] = __builtin_amdgcn_mfma_f32_16x16x32_bf16(af[mt], bf[nt], acc[mt][nt], 0, 0, 0);
        __syncthreads();
    }

    // Q scale folds softmax 1/sqrt(1024) AND log2(e) (attn softmax in exp2 domain)
    const float scale = (z == 0) ? (0.03125f * 1.44269504f) : 1.0f;
#pragma unroll
    for (int mt = 0; mt < 4; ++mt) {
#pragma unroll
        for (int nt = 0; nt < 4; ++nt) {
#pragma unroll
            for (int b = 0; b < 4; ++b) {
                int m = m0 + wm * 64 + mt * 16 + hi * 4 + b;
                int n = n0 + wn * 64 + nt * 16 + col;
                int bidx = m >> 11, s = m & 2047;
                int h = n >> 6, d = n & 63;
                size_t off = (((size_t)(bidx * NHEAD + h)) * S_LEN + s) * HDIM + d;
                Out[off] = f2bf(acc[mt][nt][b] * scale);
            }
        }
    }
}

// ---------------- causal flash attention (KVBLK=256, 4 barrier-free sub-tiles) -------
// 512 blocks x 512 threads; block = one 256-row q-tile (8 waves x 32 q-rows).
// Complementary-qt pairing: CU c hosts qt and 7-qt (uniform per-CU work).
__global__ __launch_bounds__(512, 2) void attn_fwd(
        const unsigned short* __restrict__ Q,
        const unsigned short* __restrict__ K,
        const unsigned short* __restrict__ V,
        unsigned short* __restrict__ Out) {
    const int g = blockIdx.x;                 // 0..511
    const int k8 = g >> 6;                    // 0..7
    const int qt = (k8 < 4) ? (7 - k8) : (k8 - 4); // pair sums to 7 per CU
    const int bh = (g & 7) + ((g >> 3) & 7) * 8;  // same-bh blocks share g%8 -> same XCD
    const int b_idx = bh >> 4, h = bh & 15;
    const int tid = threadIdx.x, lane = tid & 63, w = tid >> 6;  // w: 0..7
    const int l31 = lane & 31, b5 = lane >> 5;
    const bool lo32 = (b5 == 0);
    const int rsw = (l31 & 7) << 3;           // read swizzle (rows r and r+32 share &7)

    const unsigned short* Qb = Q + (size_t)bh * (S_LEN * HDIM);
    const unsigned short* Kb = K + (size_t)bh * (S_LEN * HDIM);
    const unsigned short* Vb = V + (size_t)bh * (S_LEN * HDIM);

    __shared__ __align__(16) unsigned short Klds[256 * 64];  // [kv][d], XOR-swizzled (32KB)
    __shared__ __align__(16) unsigned short Vt[64 * 256];    // [d][kv], XOR-swizzled (32KB)

    // K staging via global_load_lds: wave w, chunk i covers rows 8*(8i+w)..+7.
    // LDS linear; swizzle achieved by pre-swizzling the GLOBAL column:
    const int krl  = lane >> 3;                            // row-within-8 (= row&7)
    const int kcsw = ((lane & 7) * 8) ^ (krl << 3);        // pre-swizzled col
    // V staging: thread owns row vr, d-chunk vc8 of each 64-row sub-tile
    const int vr = tid & 63, vc8 = (tid >> 6) * 8;

    const int nt = qt + 1;                 // 256-row kv chunks
    const int q0w = qt * 256 + w * 32;     // wave's 32-row strip
    const int qg = q0w + l31;              // this lane's q-row

    // Q fragments: qf[dc] = Q[qg][dc*16 + 8*b5 .. +7]
    short8 qf[4];
    {
        const unsigned short* qrow = Qb + (size_t)qg * HDIM;
#pragma unroll
        for (int dc = 0; dc < 4; ++dc)
            qf[dc] = *reinterpret_cast<const short8*>(qrow + dc * 16 + b5 * 8);
    }

    f32x16 ot0 = {}, ot1 = {};   // O^T accumulators
    float mrun = -INFINITY, lsum = 0.f;

    // prefetch V chunk 0 (4 x 64-row sub-tiles, one short8 each)
    short8 pv0 = *reinterpret_cast<const short8*>(Vb + (size_t)(vr) * HDIM + vc8);
    short8 pv1 = *reinterpret_cast<const short8*>(Vb + (size_t)(64 + vr) * HDIM + vc8);
    short8 pv2 = *reinterpret_cast<const short8*>(Vb + (size_t)(128 + vr) * HDIM + vc8);
    short8 pv3 = *reinterpret_cast<const short8*>(Vb + (size_t)(192 + vr) * HDIM + vc8);

    for (int t = 0; t < nt; ++t) {
        const int kv0 = t * 256;
        __syncthreads();   // prior step's LDS reads complete
        // K: 4 async 1KB chunks per wave, pre-swizzled global source
#pragma unroll
        for (int i = 0; i < 4; ++i) {
            const int rowbase = 8 * (8 * i + w);
            GLD16(Kb + (size_t)(kv0 + rowbase + krl) * HDIM + kcsw,
                  &Klds[rowbase * 64]);
        }
        // V: transposed swizzled writes from prefetched regs
#pragma unroll
        for (int j = 0; j < 8; ++j) {
            const int d0 = vc8 + j;
            const int sj = (d0 & 7) << 3;
            Vt[d0 * 256 + ((vr)       ^ sj)] = (unsigned short)pv0[j];
            Vt[d0 * 256 + ((64 + vr)  ^ sj)] = (unsigned short)pv1[j];
            Vt[d0 * 256 + ((128 + vr) ^ sj)] = (unsigned short)pv2[j];
            Vt[d0 * 256 + ((192 + vr) ^ sj)] = (unsigned short)pv3[j];
        }
        if (t < nt - 1) { // prefetch next V chunk
            const int kn = kv0 + 256;
            pv0 = *reinterpret_cast<const short8*>(Vb + (size_t)(kn + vr) * HDIM + vc8);
            pv1 = *reinterpret_cast<const short8*>(Vb + (size_t)(kn + 64 + vr) * HDIM + vc8);
            pv2 = *reinterpret_cast<const short8*>(Vb + (size_t)(kn + 128 + vr) * HDIM + vc8);
            pv3 = *reinterpret_cast<const short8*>(Vb + (size_t)(kn + 192 + vr) * HDIM + vc8);
        }
        __syncthreads();   // drains global_load_lds; staging visible

        // 4 kv sub-tiles, no barriers between (softmax state in registers)
#pragma unroll
        for (int s4 = 0; s4 < 4; ++s4) {
            const int kvs = kv0 + 64 * s4;
            if (kvs > q0w + 31) break;   // wave-uniform, monotone
            const int ksb = 64 * s4;

            // S^T = K Q^T: rows k (regs), col q (lane&31)
            f32x16 st0 = {}, st1 = {};
            __builtin_amdgcn_s_setprio(1);
#pragma unroll
            for (int dc = 0; dc < 4; ++dc) {
                const int co = dc * 16 + b5 * 8;
                short8 kfA = *reinterpret_cast<const short8*>(&Klds[(ksb + l31) * 64 + (co ^ rsw)]);
                short8 kfB = *reinterpret_cast<const short8*>(&Klds[(ksb + 32 + l31) * 64 + (co ^ rsw)]);
                st0 = __builtin_amdgcn_mfma_f32_32x32x16_bf16(kfA, qf[dc], st0, 0, 0, 0);
                st1 = __builtin_amdgcn_mfma_f32_32x32x16_bf16(kfB, qf[dc], st1, 0, 0, 0);
            }
            __builtin_amdgcn_s_setprio(0);

            if (kvs + 63 > q0w) { // diagonal-overlap: causal mask
#pragma unroll
                for (int r = 0; r < 16; ++r) {
                    const int krow = (r & 3) + 8 * (r >> 2) + 4 * b5;
                    if (kvs + krow > qg)      st0[r] = -INFINITY;
                    if (kvs + 32 + krow > qg) st1[r] = -INFINITY;
                }
            }

            // row max: pairwise tree (depth 6) + partner merge
            float tm0 = fmaxf(st0[0], st1[0]), tm1 = fmaxf(st0[1], st1[1]);
            float tm2 = fmaxf(st0[2], st1[2]), tm3 = fmaxf(st0[3], st1[3]);
            float tm4 = fmaxf(st0[4], st1[4]), tm5 = fmaxf(st0[5], st1[5]);
            float tm6 = fmaxf(st0[6], st1[6]), tm7 = fmaxf(st0[7], st1[7]);
            tm0 = fmaxf(tm0, fmaxf(st0[8],  st1[8]));
            tm1 = fmaxf(tm1, fmaxf(st0[9],  st1[9]));
            tm2 = fmaxf(tm2, fmaxf(st0[10], st1[10]));
            tm3 = fmaxf(tm3, fmaxf(st0[11], st1[11]));
            tm4 = fmaxf(tm4, fmaxf(st0[12], st1[12]));
            tm5 = fmaxf(tm5, fmaxf(st0[13], st1[13]));
            tm6 = fmaxf(tm6, fmaxf(st0[14], st1[14]));
            tm7 = fmaxf(tm7, fmaxf(st0[15], st1[15]));
            tm0 = fmaxf(tm0, tm4); tm1 = fmaxf(tm1, tm5);
            tm2 = fmaxf(tm2, tm6); tm3 = fmaxf(tm3, tm7);
            float vm = fmaxf(fmaxf(tm0, tm1), fmaxf(tm2, tm3));
            vm = fmaxf(vm, __shfl_xor(vm, 32));
            // defer-max (T13): rescale only when growth > 11.5 (=8 nats)
            if (__any(vm > mrun + 11.5f)) {
                const float mnew = fmaxf(mrun, vm);
                const float fac = exp2f(mrun - mnew);
                mrun = mnew;
                lsum *= fac;
#pragma unroll
                for (int r = 0; r < 16; ++r) { ot0[r] *= fac; ot1[r] *= fac; }
            }

            // per 16-k chunk: exp2 -> cvt_pk -> half-swap -> PV mfma
#pragma unroll
            for (int kc = 0; kc < 4; ++kc) {
                const int r0 = (kc & 1) * 8;
                float pe[8];
#pragma unroll
                for (int i = 0; i < 8; ++i) {
                    const float sv = (kc < 2) ? st0[r0 + i] : st1[r0 + i];
                    pe[i] = exp2f(sv - mrun);
                    lsum += pe[i];
                }
                const unsigned int W0 = cvt_pk_bf16(pe[0], pe[1]);
                const unsigned int W1 = cvt_pk_bf16(pe[2], pe[3]);
                const unsigned int W2 = cvt_pk_bf16(pe[4], pe[5]);
                const unsigned int W3 = cvt_pk_bf16(pe[6], pe[7]);
                const unsigned int t0 = (unsigned int)__shfl_xor((int)W0, 32);
                const unsigned int t1 = (unsigned int)__shfl_xor((int)W1, 32);
                const unsigned int t2 = (unsigned int)__shfl_xor((int)W2, 32);
                const unsigned int t3 = (unsigned int)__shfl_xor((int)W3, 32);
                i32x4 wv;
                wv[0] = (int)(lo32 ? W0 : t2);
                wv[1] = (int)(lo32 ? W1 : t3);
                wv[2] = (int)(lo32 ? t0 : W2);
                wv[3] = (int)(lo32 ? t1 : W3);
                const short8 pf = __builtin_bit_cast(short8, wv);

                const int ck = ksb + kc * 16 + b5 * 8;
                short8 vf0 = *reinterpret_cast<const short8*>(&Vt[l31 * 256 + (ck ^ rsw)]);
                short8 vf1 = *reinterpret_cast<const short8*>(&Vt[(32 + l31) * 256 + (ck ^ rsw)]);
                __builtin_amdgcn_s_setprio(1);
                ot0 = __builtin_amdgcn_mfma_f32_32x32x16_bf16(vf0, pf, ot0, 0, 0, 0);
                ot1 = __builtin_amdgcn_mfma_f32_32x32x16_bf16(vf1, pf, ot1, 0, 0, 0);
                __builtin_amdgcn_s_setprio(0);
            }
        }
    }

    // finalize: merge partner's l, divide, store dword pairs
    const float lfull = lsum + __shfl_xor(lsum, 32);
    const float inv = 1.0f / lfull;
    const size_t base = ((size_t)(b_idx * S_LEN + qg)) * E_DIM + h * HDIM;
#pragma unroll
    for (int r2 = 0; r2 < 8; ++r2) {
        const int d0 = 2 * (r2 & 1) + 8 * (r2 >> 1) + 4 * b5;
        const unsigned int u0 = cvt_pk_bf16(ot0[2 * r2] * inv, ot0[2 * r2 + 1] * inv);
        const unsigned int u1 = cvt_pk_bf16(ot1[2 * r2] * inv, ot1[2 * r2 + 1] * inv);
        *reinterpret_cast<unsigned int*>(const_cast<unsigned short*>(Out) + base + d0) = u0;
        *reinterpret_cast<unsigned int*>(const_cast<unsigned short*>(Out) + base + 32 + d0) = u1;
    }
}

// ---------------- output projection GEMM + bias (global_load_lds staging) ----------------
__global__ __launch_bounds__(256) void gemm_out(
        const unsigned short* __restrict__ Ab,
        const unsigned short* __restrict__ Bw,
        const float* __restrict__ bias,
        float* __restrict__ Out) {
    const int m0 = blockIdx.x * 128, n0 = blockIdx.y * 128;
    const int tid = threadIdx.x;
    const int lane = tid & 63, w = tid >> 6;
    const int wm = w >> 1, wn = w & 1;
    const int col = lane & 15, hi = lane >> 4;

    __shared__ __align__(16) unsigned short Alds[128 * 32];
    __shared__ __align__(16) unsigned short Blds[128 * 32];

    const int srow = tid >> 2;
    const int sc8  = (tid & 3) * 8;
    const int wofs = w * 512;

    f32x4 acc[4][4] = {};

    for (int kt = 0; kt < E_DIM / 32; ++kt) {
        const int k0 = kt * 32;
        GLD16(Ab + (size_t)(m0 + srow) * E_DIM + k0 + sc8,       &Alds[wofs]);
        GLD16(Ab + (size_t)(m0 + 64 + srow) * E_DIM + k0 + sc8,  &Alds[2048 + wofs]);
        GLD16(Bw + (size_t)(n0 + srow) * E_DIM + k0 + sc8,       &Blds[wofs]);
        GLD16(Bw + (size_t)(n0 + 64 + srow) * E_DIM + k0 + sc8,  &Blds[2048 + wofs]);
        __syncthreads();
        short8 af[4], bf[4];
#pragma unroll
        for (int mt = 0; mt < 4; ++mt)
            af[mt] = *reinterpret_cast<const short8*>(&Alds[(wm * 64 + mt * 16 + col) * 32 + hi * 8]);
#pragma unroll
        for (int nt = 0; nt < 4; ++nt)
            bf[nt] = *reinterpret_cast<const short8*>(&Blds[(wn * 64 + nt * 16 + col) * 32 + hi * 8]);
#pragma unroll
        for (int mt = 0; mt < 4; ++mt)
#pragma unroll
            for (int nt = 0; nt < 4; ++nt)
                acc[mt][nt] = __builtin_amdgcn_mfma_f32_16x16x32_bf16(af[mt], bf[nt], acc[mt][nt], 0, 0, 0);
        __syncthreads();
    }

#pragma unroll
    for (int mt = 0; mt < 4; ++mt) {
#pragma unroll
        for (int nt = 0; nt < 4; ++nt) {
#pragma unroll
            for (int b = 0; b < 4; ++b) {
                int m = m0 + wm * 64 + mt * 16 + hi * 4 + b;
                int n = n0 + wn * 64 + nt * 16 + col;
                Out[(size_t)m * E_DIM + n] = acc[mt][nt][b] + bias[n];
            }
        }
    }
}

extern "C" void kernel_launch(void* const* d_in, const int* in_sizes, int n_in,
                              void* d_out, int out_size, void* d_ws, size_t ws_size,
                              hipStream_t stream) {
    const float* x  = (const float*)d_in[0];
    const float* Wq = (const float*)d_in[1];
    const float* Wk = (const float*)d_in[2];
    const float* Wv = (const float*)d_in[3];
    const float* Wo = (const float*)d_in[4];
    const float* bo = (const float*)d_in[5];
    float* out = (float*)d_out;

    unsigned short* ws   = (unsigned short*)d_ws;
    unsigned short* xb   = ws;
    unsigned short* wb   = xb + (size_t)8192 * 1024;
    unsigned short* qkv  = wb + (size_t)4 * 1024 * 1024;
    unsigned short* attn = qkv + (size_t)3 * 8192 * 1024;

    cvt_all<<<12288, 256, 0, stream>>>(x, Wq, Wk, Wv, Wo, xb, wb);
    gemm_qkv<<<dim3(64, 8, 3), 256, 0, stream>>>(xb, wb, qkv);
    attn_fwd<<<512, 512, 0, stream>>>(qkv, qkv + 8388608, qkv + 2 * 8388608, attn);
    gemm_out<<<dim3(64, 8), 256, 0, stream>>>(attn, wb + 3 * 1048576, bo, out);
}

// Round 16
// 177.159 us; speedup vs baseline: 1.0852x; 1.0852x over previous
//
#include <hip/hip_runtime.h>

// Self-attention: B=4, S=2048, E=1024, H=16, D=64, causal, scale=1/32, fp32 I/O.
// Pipeline: cvt->bf16 (1 launch), QKV GEMM (MFMA + global_load_lds),
// flash attention (32x32 swapped-operand, in-register softmax, KVBLK=256),
// out GEMM (global_load_lds) + bias.
// R16: revert R15 pairing (dispatch-order gamble broke LPT: 88->103us) to
// R14's descending-qt map. Two VALU cuts in the verified body:
// (1) permlane32_swap replaces 16 shfl_xor + 16 selects per sub-tile (T12),
// (2) tree-summed lsum (serial 32-add chain -> depth-3 trees + 4 adds).

#define E_DIM 1024
#define S_LEN 2048
#define BATCH 4
#define NHEAD 16
#define HDIM  64

using short8 = __attribute__((ext_vector_type(8))) short;
using f32x4  = __attribute__((ext_vector_type(4))) float;
using f32x16 = __attribute__((ext_vector_type(16))) float;
using i32x4  = __attribute__((ext_vector_type(4))) int;
using u32x2  = __attribute__((ext_vector_type(2))) unsigned int;

// async global->LDS, 16B per lane; lds dest = wave-uniform base + lane*16
#define GLD16(gp, lp) __builtin_amdgcn_global_load_lds( \
    (const __attribute__((address_space(1))) void*)(gp), \
    (__attribute__((address_space(3))) void*)(lp), 16, 0, 0)

__device__ inline unsigned short f2bf(float f) {
    unsigned int u = __builtin_bit_cast(unsigned int, f);
    u += 0x7FFFu + ((u >> 16) & 1u);   // round-to-nearest-even
    return (unsigned short)(u >> 16);
}

// packed f32 pair -> bf16x2 (lo16 = a, hi16 = b)
__device__ inline unsigned int cvt_pk_bf16(float a, float b) {
    unsigned int r;
    asm("v_cvt_pk_bf16_f32 %0, %1, %2" : "=v"(r) : "v"(a), "v"(b));
    return r;
}

// ---------------- fused fp32 -> bf16 convert (x + 4 weights, one launch) ----------------
__global__ __launch_bounds__(256) void cvt_all(
        const float* __restrict__ x,  const float* __restrict__ wq,
        const float* __restrict__ wk, const float* __restrict__ wv,
        const float* __restrict__ wo,
        unsigned short* __restrict__ xb, unsigned short* __restrict__ wb) {
    const int bid = blockIdx.x;
    const float* src;
    unsigned short* dst;
    int blk;
    if (bid < 8192) { src = x; dst = xb; blk = bid; }
    else {
        const int wsel = (bid - 8192) >> 10;          // 0..3
        blk = (bid - 8192) & 1023;
        src = (wsel == 0) ? wq : (wsel == 1) ? wk : (wsel == 2) ? wv : wo;
        dst = wb + (size_t)wsel * 1048576;
    }
    const int i = (blk * 256 + threadIdx.x) * 4;
    float4 v = *reinterpret_cast<const float4*>(src + i);
    ushort4 o;
    o.x = f2bf(v.x); o.y = f2bf(v.y); o.z = f2bf(v.z); o.w = f2bf(v.w);
    *reinterpret_cast<ushort4*>(dst + i) = o;
}

// ---------------- QKV projection GEMM (global_load_lds staging) ----------------
__global__ __launch_bounds__(256) void gemm_qkv(
        const unsigned short* __restrict__ xb,
        const unsigned short* __restrict__ wb,
        unsigned short* __restrict__ qkv) {
    const int z = blockIdx.z;
    const unsigned short* Bw = wb + (size_t)z * (E_DIM * E_DIM);
    unsigned short* Out = qkv + (size_t)z * ((size_t)BATCH * NHEAD * S_LEN * HDIM);
    const int m0 = blockIdx.x * 128, n0 = blockIdx.y * 128;
    const int tid = threadIdx.x;
    const int lane = tid & 63, w = tid >> 6;
    const int wm = w >> 1, wn = w & 1;
    const int col = lane & 15, hi = lane >> 4;

    __shared__ __align__(16) unsigned short Alds[128 * 32];
    __shared__ __align__(16) unsigned short Blds[128 * 32];

    const int srow = tid >> 2;               // 0..63
    const int sc8  = (tid & 3) * 8;          // k-chunk
    const int wofs = w * 512;                // wave-uniform LDS base (elements)

    f32x4 acc[4][4] = {};

    for (int kt = 0; kt < E_DIM / 32; ++kt) {
        const int k0 = kt * 32;
        GLD16(xb + (size_t)(m0 + srow) * E_DIM + k0 + sc8,       &Alds[wofs]);
        GLD16(xb + (size_t)(m0 + 64 + srow) * E_DIM + k0 + sc8,  &Alds[2048 + wofs]);
        GLD16(Bw + (size_t)(n0 + srow) * E_DIM + k0 + sc8,       &Blds[wofs]);
        GLD16(Bw + (size_t)(n0 + 64 + srow) * E_DIM + k0 + sc8,  &Blds[2048 + wofs]);
        __syncthreads();
        short8 af[4], bf[4];
#pragma unroll
        for (int mt = 0; mt < 4; ++mt)
            af[mt] = *reinterpret_cast<const short8*>(&Alds[(wm * 64 + mt * 16 + col) * 32 + hi * 8]);
#pragma unroll
        for (int nt = 0; nt < 4; ++nt)
            bf[nt] = *reinterpret_cast<const short8*>(&Blds[(wn * 64 + nt * 16 + col) * 32 + hi * 8]);
#pragma unroll
        for (int mt = 0; mt < 4; ++mt)
#pragma unroll
            for (int nt = 0; nt < 4; ++nt)
                acc[mt][nt] = __builtin_amdgcn_mfma_f32_16x16x32_bf16(af[mt], bf[nt], acc[mt][nt], 0, 0, 0);
        __syncthreads();
    }

    // Q scale folds softmax 1/sqrt(1024) AND log2(e) (attn softmax in exp2 domain)
    const float scale = (z == 0) ? (0.03125f * 1.44269504f) : 1.0f;
#pragma unroll
    for (int mt = 0; mt < 4; ++mt) {
#pragma unroll
        for (int nt = 0; nt < 4; ++nt) {
#pragma unroll
            for (int b = 0; b < 4; ++b) {
                int m = m0 + wm * 64 + mt * 16 + hi * 4 + b;
                int n = n0 + wn * 64 + nt * 16 + col;
                int bidx = m >> 11, s = m & 2047;
                int h = n >> 6, d = n & 63;
                size_t off = (((size_t)(bidx * NHEAD + h)) * S_LEN + s) * HDIM + d;
                Out[off] = f2bf(acc[mt][nt][b] * scale);
            }
        }
    }
}

// ---------------- causal flash attention (KVBLK=256, 4 barrier-free sub-tiles) -------
// 512 blocks x 512 threads; block = one 256-row q-tile (8 waves x 32 q-rows).
// Descending-qt LPT dispatch (R14 map, proven).
__global__ __launch_bounds__(512, 2) void attn_fwd(
        const unsigned short* __restrict__ Q,
        const unsigned short* __restrict__ K,
        const unsigned short* __restrict__ V,
        unsigned short* __restrict__ Out) {
    const int g = blockIdx.x;                 // 0..511
    const int qt = 7 - (g >> 6);              // 256-row q-tile, longest first (LPT)
    const int bh = (g & 7) + ((g >> 3) & 7) * 8;  // same-bh blocks share g%8 -> same XCD
    const int b_idx = bh >> 4, h = bh & 15;
    const int tid = threadIdx.x, lane = tid & 63, w = tid >> 6;  // w: 0..7
    const int l31 = lane & 31, b5 = lane >> 5;
    const int rsw = (l31 & 7) << 3;           // read swizzle (rows r and r+32 share &7)

    const unsigned short* Qb = Q + (size_t)bh * (S_LEN * HDIM);
    const unsigned short* Kb = K + (size_t)bh * (S_LEN * HDIM);
    const unsigned short* Vb = V + (size_t)bh * (S_LEN * HDIM);

    __shared__ __align__(16) unsigned short Klds[256 * 64];  // [kv][d], XOR-swizzled (32KB)
    __shared__ __align__(16) unsigned short Vt[64 * 256];    // [d][kv], XOR-swizzled (32KB)

    // K staging via global_load_lds: wave w, chunk i covers rows 8*(8i+w)..+7.
    // LDS linear; swizzle achieved by pre-swizzling the GLOBAL column:
    const int krl  = lane >> 3;                            // row-within-8 (= row&7)
    const int kcsw = ((lane & 7) * 8) ^ (krl << 3);        // pre-swizzled col
    // V staging: thread owns row vr, d-chunk vc8 of each 64-row sub-tile
    const int vr = tid & 63, vc8 = (tid >> 6) * 8;

    const int nt = qt + 1;                 // 256-row kv chunks
    const int q0w = qt * 256 + w * 32;     // wave's 32-row strip
    const int qg = q0w + l31;              // this lane's q-row

    // Q fragments: qf[dc] = Q[qg][dc*16 + 8*b5 .. +7]
    short8 qf[4];
    {
        const unsigned short* qrow = Qb + (size_t)qg * HDIM;
#pragma unroll
        for (int dc = 0; dc < 4; ++dc)
            qf[dc] = *reinterpret_cast<const short8*>(qrow + dc * 16 + b5 * 8);
    }

    f32x16 ot0 = {}, ot1 = {};   // O^T accumulators
    float mrun = -INFINITY, lsum = 0.f;

    // prefetch V chunk 0 (4 x 64-row sub-tiles, one short8 each)
    short8 pv0 = *reinterpret_cast<const short8*>(Vb + (size_t)(vr) * HDIM + vc8);
    short8 pv1 = *reinterpret_cast<const short8*>(Vb + (size_t)(64 + vr) * HDIM + vc8);
    short8 pv2 = *reinterpret_cast<const short8*>(Vb + (size_t)(128 + vr) * HDIM + vc8);
    short8 pv3 = *reinterpret_cast<const short8*>(Vb + (size_t)(192 + vr) * HDIM + vc8);

    for (int t = 0; t < nt; ++t) {
        const int kv0 = t * 256;
        __syncthreads();   // prior step's LDS reads complete
        // K: 4 async 1KB chunks per wave, pre-swizzled global source
#pragma unroll
        for (int i = 0; i < 4; ++i) {
            const int rowbase = 8 * (8 * i + w);
            GLD16(Kb + (size_t)(kv0 + rowbase + krl) * HDIM + kcsw,
                  &Klds[rowbase * 64]);
        }
        // V: transposed swizzled writes from prefetched regs
#pragma unroll
        for (int j = 0; j < 8; ++j) {
            const int d0 = vc8 + j;
            const int sj = (d0 & 7) << 3;
            Vt[d0 * 256 + ((vr)       ^ sj)] = (unsigned short)pv0[j];
            Vt[d0 * 256 + ((64 + vr)  ^ sj)] = (unsigned short)pv1[j];
            Vt[d0 * 256 + ((128 + vr) ^ sj)] = (unsigned short)pv2[j];
            Vt[d0 * 256 + ((192 + vr) ^ sj)] = (unsigned short)pv3[j];
        }
        if (t < nt - 1) { // prefetch next V chunk
            const int kn = kv0 + 256;
            pv0 = *reinterpret_cast<const short8*>(Vb + (size_t)(kn + vr) * HDIM + vc8);
            pv1 = *reinterpret_cast<const short8*>(Vb + (size_t)(kn + 64 + vr) * HDIM + vc8);
            pv2 = *reinterpret_cast<const short8*>(Vb + (size_t)(kn + 128 + vr) * HDIM + vc8);
            pv3 = *reinterpret_cast<const short8*>(Vb + (size_t)(kn + 192 + vr) * HDIM + vc8);
        }
        __syncthreads();   // drains global_load_lds; staging visible

        // 4 kv sub-tiles, no barriers between (softmax state in registers)
#pragma unroll
        for (int s4 = 0; s4 < 4; ++s4) {
            const int kvs = kv0 + 64 * s4;
            if (kvs > q0w + 31) break;   // wave-uniform, monotone
            const int ksb = 64 * s4;

            // S^T = K Q^T: rows k (regs), col q (lane&31)
            f32x16 st0 = {}, st1 = {};
            __builtin_amdgcn_s_setprio(1);
#pragma unroll
            for (int dc = 0; dc < 4; ++dc) {
                const int co = dc * 16 + b5 * 8;
                short8 kfA = *reinterpret_cast<const short8*>(&Klds[(ksb + l31) * 64 + (co ^ rsw)]);
                short8 kfB = *reinterpret_cast<const short8*>(&Klds[(ksb + 32 + l31) * 64 + (co ^ rsw)]);
                st0 = __builtin_amdgcn_mfma_f32_32x32x16_bf16(kfA, qf[dc], st0, 0, 0, 0);
                st1 = __builtin_amdgcn_mfma_f32_32x32x16_bf16(kfB, qf[dc], st1, 0, 0, 0);
            }
            __builtin_amdgcn_s_setprio(0);

            if (kvs + 63 > q0w) { // diagonal-overlap: causal mask
#pragma unroll
                for (int r = 0; r < 16; ++r) {
                    const int krow = (r & 3) + 8 * (r >> 2) + 4 * b5;
                    if (kvs + krow > qg)      st0[r] = -INFINITY;
                    if (kvs + 32 + krow > qg) st1[r] = -INFINITY;
                }
            }

            // row max: pairwise tree (depth 6) + partner merge
            float tm0 = fmaxf(st0[0], st1[0]), tm1 = fmaxf(st0[1], st1[1]);
            float tm2 = fmaxf(st0[2], st1[2]), tm3 = fmaxf(st0[3], st1[3]);
            float tm4 = fmaxf(st0[4], st1[4]), tm5 = fmaxf(st0[5], st1[5]);
            float tm6 = fmaxf(st0[6], st1[6]), tm7 = fmaxf(st0[7], st1[7]);
            tm0 = fmaxf(tm0, fmaxf(st0[8],  st1[8]));
            tm1 = fmaxf(tm1, fmaxf(st0[9],  st1[9]));
            tm2 = fmaxf(tm2, fmaxf(st0[10], st1[10]));
            tm3 = fmaxf(tm3, fmaxf(st0[11], st1[11]));
            tm4 = fmaxf(tm4, fmaxf(st0[12], st1[12]));
            tm5 = fmaxf(tm5, fmaxf(st0[13], st1[13]));
            tm6 = fmaxf(tm6, fmaxf(st0[14], st1[14]));
            tm7 = fmaxf(tm7, fmaxf(st0[15], st1[15]));
            tm0 = fmaxf(tm0, tm4); tm1 = fmaxf(tm1, tm5);
            tm2 = fmaxf(tm2, tm6); tm3 = fmaxf(tm3, tm7);
            float vm = fmaxf(fmaxf(tm0, tm1), fmaxf(tm2, tm3));
            vm = fmaxf(vm, __shfl_xor(vm, 32));
            // defer-max (T13): rescale only when growth > 11.5 (=8 nats)
            if (__any(vm > mrun + 11.5f)) {
                const float mnew = fmaxf(mrun, vm);
                const float fac = exp2f(mrun - mnew);
                mrun = mnew;
                lsum *= fac;
#pragma unroll
                for (int r = 0; r < 16; ++r) { ot0[r] *= fac; ot1[r] *= fac; }
            }

            // per 16-k chunk: exp2 -> cvt_pk -> permlane32 half-swap -> PV mfma
#pragma unroll
            for (int kc = 0; kc < 4; ++kc) {
                const int r0 = (kc & 1) * 8;
                float pe[8];
#pragma unroll
                for (int i = 0; i < 8; ++i) {
                    const float sv = (kc < 2) ? st0[r0 + i] : st1[r0 + i];
                    pe[i] = exp2f(sv - mrun);
                }
                // tree-summed l (short dependency chain)
                const float ps = ((pe[0] + pe[1]) + (pe[2] + pe[3]))
                               + ((pe[4] + pe[5]) + (pe[6] + pe[7]));
                lsum += ps;
                const unsigned int W0 = cvt_pk_bf16(pe[0], pe[1]);
                const unsigned int W1 = cvt_pk_bf16(pe[2], pe[3]);
                const unsigned int W2 = cvt_pk_bf16(pe[4], pe[5]);
                const unsigned int W3 = cvt_pk_bf16(pe[6], pe[7]);
                // half-swap via permlane32_swap (T12): r.x=[a.lo,b.lo], r.y=[a.hi,b.hi]
                u32x2 s02 = __builtin_amdgcn_permlane32_swap(W0, W2, false, false);
                u32x2 s13 = __builtin_amdgcn_permlane32_swap(W1, W3, false, false);
                i32x4 wv;
                wv[0] = (int)s02[0];
                wv[1] = (int)s13[0];
                wv[2] = (int)s02[1];
                wv[3] = (int)s13[1];
                const short8 pf = __builtin_bit_cast(short8, wv);

                const int ck = ksb + kc * 16 + b5 * 8;
                short8 vf0 = *reinterpret_cast<const short8*>(&Vt[l31 * 256 + (ck ^ rsw)]);
                short8 vf1 = *reinterpret_cast<const short8*>(&Vt[(32 + l31) * 256 + (ck ^ rsw)]);
                __builtin_amdgcn_s_setprio(1);
                ot0 = __builtin_amdgcn_mfma_f32_32x32x16_bf16(vf0, pf, ot0, 0, 0, 0);
                ot1 = __builtin_amdgcn_mfma_f32_32x32x16_bf16(vf1, pf, ot1, 0, 0, 0);
                __builtin_amdgcn_s_setprio(0);
            }
        }
    }

    // finalize: merge partner's l, divide, store dword pairs
    const float lfull = lsum + __shfl_xor(lsum, 32);
    const float inv = 1.0f / lfull;
    const size_t base = ((size_t)(b_idx * S_LEN + qg)) * E_DIM + h * HDIM;
#pragma unroll
    for (int r2 = 0; r2 < 8; ++r2) {
        const int d0 = 2 * (r2 & 1) + 8 * (r2 >> 1) + 4 * b5;
        const unsigned int u0 = cvt_pk_bf16(ot0[2 * r2] * inv, ot0[2 * r2 + 1] * inv);
        const unsigned int u1 = cvt_pk_bf16(ot1[2 * r2] * inv, ot1[2 * r2 + 1] * inv);
        *reinterpret_cast<unsigned int*>(const_cast<unsigned short*>(Out) + base + d0) = u0;
        *reinterpret_cast<unsigned int*>(const_cast<unsigned short*>(Out) + base + 32 + d0) = u1;
    }
}

// ---------------- output projection GEMM + bias (global_load_lds staging) ----------------
__global__ __launch_bounds__(256) void gemm_out(
        const unsigned short* __restrict__ Ab,
        const unsigned short* __restrict__ Bw,
        const float* __restrict__ bias,
        float* __restrict__ Out) {
    const int m0 = blockIdx.x * 128, n0 = blockIdx.y * 128;
    const int tid = threadIdx.x;
    const int lane = tid & 63, w = tid >> 6;
    const int wm = w >> 1, wn = w & 1;
    const int col = lane & 15, hi = lane >> 4;

    __shared__ __align__(16) unsigned short Alds[128 * 32];
    __shared__ __align__(16) unsigned short Blds[128 * 32];

    const int srow = tid >> 2;
    const int sc8  = (tid & 3) * 8;
    const int wofs = w * 512;

    f32x4 acc[4][4] = {};

    for (int kt = 0; kt < E_DIM / 32; ++kt) {
        const int k0 = kt * 32;
        GLD16(Ab + (size_t)(m0 + srow) * E_DIM + k0 + sc8,       &Alds[wofs]);
        GLD16(Ab + (size_t)(m0 + 64 + srow) * E_DIM + k0 + sc8,  &Alds[2048 + wofs]);
        GLD16(Bw + (size_t)(n0 + srow) * E_DIM + k0 + sc8,       &Blds[wofs]);
        GLD16(Bw + (size_t)(n0 + 64 + srow) * E_DIM + k0 + sc8,  &Blds[2048 + wofs]);
        __syncthreads();
        short8 af[4], bf[4];
#pragma unroll
        for (int mt = 0; mt < 4; ++mt)
            af[mt] = *reinterpret_cast<const short8*>(&Alds[(wm * 64 + mt * 16 + col) * 32 + hi * 8]);
#pragma unroll
        for (int nt = 0; nt < 4; ++nt)
            bf[nt] = *reinterpret_cast<const short8*>(&Blds[(wn * 64 + nt * 16 + col) * 32 + hi * 8]);
#pragma unroll
        for (int mt = 0; mt < 4; ++mt)
#pragma unroll
            for (int nt = 0; nt < 4; ++nt)
                acc[mt][nt] = __builtin_amdgcn_mfma_f32_16x16x32_bf16(af[mt], bf[nt], acc[mt][nt], 0, 0, 0);
        __syncthreads();
    }

#pragma unroll
    for (int mt = 0; mt < 4; ++mt) {
#pragma unroll
        for (int nt = 0; nt < 4; ++nt) {
#pragma unroll
            for (int b = 0; b < 4; ++b) {
                int m = m0 + wm * 64 + mt * 16 + hi * 4 + b;
                int n = n0 + wn * 64 + nt * 16 + col;
                Out[(size_t)m * E_DIM + n] = acc[mt][nt][b] + bias[n];
            }
        }
    }
}

extern "C" void kernel_launch(void* const* d_in, const int* in_sizes, int n_in,
                              void* d_out, int out_size, void* d_ws, size_t ws_size,
                              hipStream_t stream) {
    const float* x  = (const float*)d_in[0];
    const float* Wq = (const float*)d_in[1];
    const float* Wk = (const float*)d_in[2];
    const float* Wv = (const float*)d_in[3];
    const float* Wo = (const float*)d_in[4];
    const float* bo = (const float*)d_in[5];
    float* out = (float*)d_out;

    unsigned short* ws   = (unsigned short*)d_ws;
    unsigned short* xb   = ws;
    unsigned short* wb   = xb + (size_t)8192 * 1024;
    unsigned short* qkv  = wb + (size_t)4 * 1024 * 1024;
    unsigned short* attn = qkv + (size_t)3 * 8192 * 1024;

    cvt_all<<<12288, 256, 0, stream>>>(x, Wq, Wk, Wv, Wo, xb, wb);
    gemm_qkv<<<dim3(64, 8, 3), 256, 0, stream>>>(xb, wb, qkv);
    attn_fwd<<<512, 512, 0, stream>>>(qkv, qkv + 8388608, qkv + 2 * 8388608, attn);
    gemm_out<<<dim3(64, 8), 256, 0, stream>>>(attn, wb + 3 * 1048576, bo, out);
}